// Round 4
// baseline (2094.236 us; speedup 1.0000x reference)
//
#include <hip/hip_runtime.h>
#include <math.h>

// ---------------------------------------------------------------------------
// SENSE CG reconstruction, B=1, S=4, C=16, H=W=320, rho=0.1, 15 CG iters.
// Conjugated by fftshift (even N): CG loop uses plain FFTs; final
// ifft2c(fft2c(x)) == x skipped. FFT-320 = Stockham 5*4*4*4 in LDS, one
// wave (64 lanes) per line. Intra-FFT sync = wave fences only.
// R3->R4: passB tile 8 cols/512thr (41.5KB LDS, 3 blk/CU) -> 4 cols/256thr
//         (20.7KB, 7 blk/CU). R3 evidence: passB VALUBusy 39%, occ 33%,
//         2 TB/s -> LDS-occupancy-capped latency binding, not BW.
// ---------------------------------------------------------------------------

#define NDIM 320
#define HHALF 160
#define HW (NDIM*NDIM)
#define NS 4
#define NC 16
#define RHO_ 0.1f
#define CG_ITERS 15

__device__ __forceinline__ void wsync(){
    __builtin_amdgcn_fence(__ATOMIC_ACQ_REL, "wavefront");
    __builtin_amdgcn_wave_barrier();
}

__device__ __forceinline__ float wred(float v){
    #pragma unroll
    for (int o=32;o>0;o>>=1) v += __shfl_down(v,o,64);
    return v;  // valid on lane 0
}

__device__ __forceinline__ float2 cmulf(float2 a, float2 b){
    return make_float2(a.x*b.x - a.y*b.y, a.x*b.y + a.y*b.x);
}

template<int SIGMA>
__device__ __forceinline__ float2 cmulw(float2 a, float2 w){
    float wy = (SIGMA < 0) ? w.y : -w.y;
    return make_float2(a.x*w.x - a.y*wy, a.x*wy + a.y*w.x);
}

template<int SIGMA>
__device__ __forceinline__ void radix4(const float2* u, float2* v){
    float2 a = make_float2(u[0].x+u[2].x, u[0].y+u[2].y);
    float2 b = make_float2(u[0].x-u[2].x, u[0].y-u[2].y);
    float2 c = make_float2(u[1].x+u[3].x, u[1].y+u[3].y);
    float2 d = make_float2(u[1].x-u[3].x, u[1].y-u[3].y);
    float2 jd = make_float2(-(float)SIGMA*d.y, (float)SIGMA*d.x);
    v[0] = make_float2(a.x+c.x, a.y+c.y);
    v[1] = make_float2(b.x+jd.x, b.y+jd.y);
    v[2] = make_float2(a.x-c.x, a.y-c.y);
    v[3] = make_float2(b.x-jd.x, b.y-jd.y);
}

template<int SIGMA>
__device__ __forceinline__ void radix5(const float2* u, float2* v){
    const float C1 = 0.30901699437494742f, S1 = 0.95105651629515357f;
    const float C2 = -0.80901699437494745f, S2 = 0.58778525229247312f;
    float2 t1 = make_float2(u[1].x+u[4].x, u[1].y+u[4].y);
    float2 t2 = make_float2(u[2].x+u[3].x, u[2].y+u[3].y);
    float2 t3 = make_float2(u[1].x-u[4].x, u[1].y-u[4].y);
    float2 t4 = make_float2(u[2].x-u[3].x, u[2].y-u[3].y);
    v[0] = make_float2(u[0].x + t1.x + t2.x, u[0].y + t1.y + t2.y);
    float2 m1 = make_float2(u[0].x + C1*t1.x + C2*t2.x, u[0].y + C1*t1.y + C2*t2.y);
    float2 m2 = make_float2(u[0].x + C2*t1.x + C1*t2.x, u[0].y + C2*t1.y + C1*t2.y);
    float2 n1 = make_float2(S1*t3.x + S2*t4.x, S1*t3.y + S2*t4.y);
    float2 n2 = make_float2(S2*t3.x - S1*t4.x, S2*t3.y - S1*t4.y);
    float2 j1 = make_float2(-(float)SIGMA*n1.y, (float)SIGMA*n1.x);
    float2 j2 = make_float2(-(float)SIGMA*n2.y, (float)SIGMA*n2.x);
    v[1] = make_float2(m1.x + j1.x, m1.y + j1.y);
    v[4] = make_float2(m1.x - j1.x, m1.y - j1.y);
    v[2] = make_float2(m2.x + j2.x, m2.y + j2.y);
    v[3] = make_float2(m2.x - j2.x, m2.y - j2.y);
}

struct Tw { float2 w20a, w20b, w80a, w80b, w320a, w320b; };

__device__ __forceinline__ Tw make_tw(int t){
    Tw tw; float sn, cs;
    const float n2pi = -6.283185307179586f;
    __sincosf(n2pi*(float)(t%5)    /20.f,  &sn,&cs); tw.w20a = make_float2(cs,sn);
    __sincosf(n2pi*(float)((t+4)%5)/20.f,  &sn,&cs); tw.w20b = make_float2(cs,sn);
    __sincosf(n2pi*(float)(t%20)    /80.f, &sn,&cs); tw.w80a = make_float2(cs,sn);
    __sincosf(n2pi*(float)((t+4)%20)/80.f, &sn,&cs); tw.w80b = make_float2(cs,sn);
    __sincosf(n2pi*(float)t      /320.f,   &sn,&cs); tw.w320a= make_float2(cs,sn);
    __sincosf(n2pi*(float)(t+64) /320.f,   &sn,&cs); tw.w320b= make_float2(cs,sn);
    return tw;
}

template<int SIGMA>
__device__ __forceinline__ void bfly5(const float2* __restrict__ in,
                                      float2* __restrict__ out, int i){
    float2 u[5];
    #pragma unroll
    for (int q=0;q<5;++q) u[q] = in[i + q*64];
    float2 v[5];
    radix5<SIGMA>(u,v);
    #pragma unroll
    for (int c=0;c<5;++c) out[i*5 + c] = v[c];
}

template<int SIGMA, int P>
__device__ __forceinline__ void bfly4(const float2* __restrict__ in,
                                      float2* __restrict__ out, int i, float2 w1){
    const int T = 80;
    int k = i % P, jb = i / P;
    float2 u[4];
    #pragma unroll
    for (int q=0;q<4;++q) u[q] = in[i + q*T];
    float2 w2 = cmulf(w1,w1);
    float2 w3 = cmulf(w2,w1);
    u[1] = cmulw<SIGMA>(u[1], w1);
    u[2] = cmulw<SIGMA>(u[2], w2);
    u[3] = cmulw<SIGMA>(u[3], w3);
    float2 v[4];
    radix4<SIGMA>(u,v);
    int base = jb*(4*P) + k;
    #pragma unroll
    for (int c=0;c<4;++c) out[base + c*P] = v[c];
}

template<int SIGMA>
__device__ __forceinline__ void fft320w(float2* __restrict__ A,
                                        float2* __restrict__ B,
                                        int t, const Tw& tw){
    wsync();
    bfly5<SIGMA>(A,B,t);
    wsync();
    bfly4<SIGMA,5>(B,A,t, tw.w20a);
    if (t<16) bfly4<SIGMA,5>(B,A,t+64, tw.w20b);
    wsync();
    bfly4<SIGMA,20>(A,B,t, tw.w80a);
    if (t<16) bfly4<SIGMA,20>(A,B,t+64, tw.w80b);
    wsync();
    bfly4<SIGMA,80>(B,A,t, tw.w320a);
    if (t<16) bfly4<SIGMA,80>(B,A,t+64, tw.w320b);
    wsync();
}

__device__ __forceinline__ int sh160(int i){ return i < HHALF ? i + HHALF : i - HHALF; }

// ---------------------------------------------------------------------------
__global__ void k_prep(const float2* __restrict__ kin, const float* __restrict__ mask,
                       const float2* __restrict__ csm, float2* __restrict__ sP,
                       float* __restrict__ mscT, float2* __restrict__ K,
                       float* __restrict__ scal)
{
    int gid = blockIdx.x*blockDim.x + threadIdx.x;
    int gsz = gridDim.x*blockDim.x;
    if (gid < 64) scal[gid] = 0.f;
    for (int i = gid; i < NC*HW; i += gsz){
        int w = i % NDIM; int h = (i/NDIM) % NDIM; int c = i/HW;
        sP[i] = csm[(c*NDIM + sh160(h))*NDIM + sh160(w)];
    }
    for (int i = gid; i < NS*HW; i += gsz){
        int h = i % NDIM; int wc = (i/NDIM)%NDIM; int s = i/HW;
        float m = mask[(s*NDIM + sh160(h))*NDIM + sh160(wc)];
        mscT[i] = m*m*(1.0f/102400.0f);
    }
    for (int i = gid; i < NS*NC*HW; i += gsz){
        int w = i % NDIM; int h = (i/NDIM)%NDIM; int sc = i/HW;
        int s = sc >> 4;
        int hs = sh160(h), ws = sh160(w);
        float m = mask[(s*NDIM + hs)*NDIM + ws];
        float2 kv = kin[((long)sc*NDIM + hs)*NDIM + ws];
        float f = m*(1.0f/320.0f);
        K[i] = make_float2(kv.x*f, kv.y*f);
    }
}

// ---------------------------------------------------------------------------
// PassA: p = r + beta*p fused; K[s,c,h,:] = rowFFT(s'_c .* p).
__global__ __launch_bounds__(256) void k_passA(
    const float2* __restrict__ rv_, const float2* __restrict__ pOld,
    float2* __restrict__ pNew, const float2* __restrict__ sP,
    float2* __restrict__ K, float* __restrict__ scal, int iter)
{
    int bid = blockIdx.x;
    int cg = bid & 3;
    int hg = (bid>>2) % 80;
    int s  = bid / (4*80);
    int tid = threadIdx.x; int rl = tid>>6; int t = tid&63;
    int h = hg*4 + rl;
    __shared__ float2 bufA[4][NDIM];
    __shared__ float2 bufB[4][NDIM];
    float2* A = &bufA[rl][0];
    float2* B = &bufB[rl][0];
    Tw tw = make_tw(t);
    float beta = 0.f;
    if (iter > 0) beta = scal[iter] / (scal[iter-1] + 1e-12f);
    long base = (long)s*HW + h*NDIM;
    float2 pv[5];
    #pragma unroll
    for (int j=0;j<5;++j){
        int idx = t + 64*j;
        float2 rr = rv_[base+idx];
        if (iter > 0){
            float2 pp = pOld[base+idx];
            pv[j] = make_float2(rr.x + beta*pp.x, rr.y + beta*pp.y);
        } else pv[j] = rr;
    }
    if (cg == 0){
        float d = 0.f;
        #pragma unroll
        for (int j=0;j<5;++j){
            pNew[base + t + 64*j] = pv[j];
            d += pv[j].x*pv[j].x + pv[j].y*pv[j].y;
        }
        float wd = wred(d);
        if (t==0) atomicAdd(&scal[16+iter], RHO_*wd);
    }
    int c = cg*4;
    const float2* srow = sP + (long)c*HW + h*NDIM;
    float2 sv[5];
    #pragma unroll
    for (int j=0;j<5;++j) sv[j] = srow[t+64*j];
    #pragma unroll
    for (int c0=0;c0<4;++c0){
        #pragma unroll
        for (int j=0;j<5;++j) A[t+64*j] = cmulf(sv[j], pv[j]);
        float2 sv2[5];
        if (c0<3){
            const float2* sr2 = srow + (long)(c0+1)*HW;
            #pragma unroll
            for (int j=0;j<5;++j) sv2[j] = sr2[t+64*j];
        }
        fft320w<-1>(A,B,t,tw);
        long kb = ((long)(s*NC + c + c0))*HW + h*NDIM;
        #pragma unroll
        for (int j=0;j<5;++j){ int idx=t+64*j; K[kb+idx] = A[idx]; }
        wsync();
        if (c0<3){
            #pragma unroll
            for (int j=0;j<5;++j) sv[j]=sv2[j];
        }
    }
}

// ---------------------------------------------------------------------------
// PassB: per (s,c) image, 4-column LDS tile: colFFT -> mask*scale -> colIFFT
// (doMask=1) or colIFFT only (doMask=0). In-place on K.
// 256 thr = 4 waves, one column per wave; LDS 20.7KB -> 7 blocks/CU.
__global__ __launch_bounds__(256) void k_passB(float2* __restrict__ K,
    const float* __restrict__ mscT, int doMask)
{
    constexpr int L = 324;
    int bid = blockIdx.x;
    int wt = bid % 80;
    int sc = bid / 80;
    int s = sc >> 4;
    int tid = threadIdx.x;
    int col = tid >> 6;
    int t = tid & 63;
    int w0 = wt*4;
    __shared__ float2 bufA[4][L];
    __shared__ float2 bufB[4][L];
    Tw tw = make_tw(t);
    float mv[5];
    if (doMask){
        const float* mcol = mscT + (long)s*HW + (long)(w0+col)*NDIM;
        #pragma unroll
        for (int j=0;j<5;++j) mv[j] = mcol[t+64*j];
    }
    long gb = (long)sc*HW;
    int wl = tid & 3, hb = tid >> 2;  // 32B contiguous per 4 lanes
    #pragma unroll
    for (int j=0;j<5;++j){
        int hh = hb + 64*j;
        bufA[wl][hh] = K[gb + (long)hh*NDIM + w0 + wl];
    }
    __syncthreads();
    float2* A = &bufA[col][0];
    float2* B = &bufB[col][0];
    if (doMask){
        fft320w<-1>(A,B,t,tw);
        #pragma unroll
        for (int j=0;j<5;++j){
            int hh = t + 64*j;
            A[hh].x *= mv[j]; A[hh].y *= mv[j];
        }
        fft320w<1>(A,B,t,tw);
    } else {
        fft320w<1>(A,B,t,tw);
    }
    __syncthreads();
    #pragma unroll
    for (int j=0;j<5;++j){
        int hh = hb + 64*j;
        K[gb + (long)hh*NDIM + w0 + wl] = bufA[wl][hh];
    }
}

// ---------------------------------------------------------------------------
// PassC2: rowIFFT of one coil-group (4 coils), conj(s')-combine into
// part[cg]; optional partial p.part dot into scal[dotSlot].
__global__ __launch_bounds__(256) void k_passC2(
    const float2* __restrict__ K, const float2* __restrict__ sP,
    const float2* __restrict__ pVec, float2* __restrict__ part,
    float* __restrict__ scal, int dotSlot, int doDot)
{
    int bid = blockIdx.x;
    int cg = bid & 3;
    int hg = (bid>>2) % 80;
    int s  = bid / (4*80);
    int tid = threadIdx.x; int rl = tid>>6; int t = tid&63;
    int h = hg*4 + rl;
    __shared__ float2 bufA[4][NDIM];
    __shared__ float2 bufB[4][NDIM];
    __shared__ float redS[4];
    float2* A = &bufA[rl][0];
    float2* B = &bufB[rl][0];
    Tw tw = make_tw(t);
    int c = cg*4;
    long kb0 = ((long)(s*NC + c))*HW + h*NDIM;
    const float2* srow = sP + (long)c*HW + h*NDIM;
    float2 kv[5], sv[5];
    #pragma unroll
    for (int j=0;j<5;++j){ int idx=t+64*j; kv[j]=K[kb0+idx]; sv[j]=srow[idx]; }
    float2 acc[5];
    #pragma unroll
    for (int j=0;j<5;++j) acc[j]=make_float2(0.f,0.f);
    #pragma unroll
    for (int c0=0;c0<4;++c0){
        #pragma unroll
        for (int j=0;j<5;++j) A[t+64*j] = kv[j];
        float2 kv2[5], sv2[5];
        if (c0<3){
            long kb = kb0 + (long)(c0+1)*HW;
            const float2* sr2 = srow + (long)(c0+1)*HW;
            #pragma unroll
            for (int j=0;j<5;++j){ int idx=t+64*j; kv2[j]=K[kb+idx]; sv2[j]=sr2[idx]; }
        }
        fft320w<1>(A,B,t,tw);
        #pragma unroll
        for (int j=0;j<5;++j){
            float2 uv = A[t+64*j];
            acc[j].x += sv[j].x*uv.x + sv[j].y*uv.y;
            acc[j].y += sv[j].x*uv.y - sv[j].y*uv.x;
        }
        wsync();
        if (c0<3){
            #pragma unroll
            for (int j=0;j<5;++j){ kv[j]=kv2[j]; sv[j]=sv2[j]; }
        }
    }
    long pbase = (long)s*HW + h*NDIM;
    long obase = ((long)cg*NS + s)*HW + h*NDIM;
    float dot = 0.f;
    #pragma unroll
    for (int j=0;j<5;++j){
        int idx=t+64*j;
        part[obase+idx] = acc[j];
        if (doDot){
            float2 pp = pVec[pbase+idx];
            dot += pp.x*acc[j].x + pp.y*acc[j].y;
        }
    }
    if (doDot){
        float wd = wred(dot);
        if (t==0) redS[rl] = wd;
        __syncthreads();
        if (tid==0) atomicAdd(&scal[dotSlot], redS[0]+redS[1]+redS[2]+redS[3]);
    }
}

// ---------------------------------------------------------------------------
__global__ __launch_bounds__(256) void k_rhs_fin(
    const float2* __restrict__ part, const float2* __restrict__ Iin,
    float2* __restrict__ r, float2* __restrict__ x, float* __restrict__ scal)
{
    __shared__ float red[256];
    int gid = blockIdx.x*blockDim.x + threadIdx.x;
    int gsz = gridDim.x*blockDim.x;
    float rs = 0.f;
    const int NV = NS*HW;
    for (int i = gid; i < NV; i += gsz){
        int w = i % NDIM; int h = (i/NDIM)%NDIM; int s = i/HW;
        float2 iv = Iin[((long)s*NDIM + sh160(h))*NDIM + sh160(w)];
        float2 a0=part[i], a1=part[NV+i], a2=part[2*NV+i], a3=part[3*NV+i];
        float2 rr = make_float2(a0.x+a1.x+a2.x+a3.x + RHO_*iv.x,
                                a0.y+a1.y+a2.y+a3.y + RHO_*iv.y);
        r[i] = rr;
        x[i] = make_float2(0.f,0.f);
        rs += rr.x*rr.x + rr.y*rr.y;
    }
    red[threadIdx.x]=rs; __syncthreads();
    for (int o=128;o>0;o>>=1){ if (threadIdx.x<o) red[threadIdx.x]+=red[threadIdx.x+o]; __syncthreads(); }
    if (threadIdx.x==0) atomicAdd(&scal[0], red[0]);
}

// ---------------------------------------------------------------------------
__global__ __launch_bounds__(256) void k_update(
    float2* __restrict__ x, float2* __restrict__ r,
    const float2* __restrict__ p, const float2* __restrict__ part,
    float* __restrict__ scal, int iter)
{
    __shared__ float red[256];
    float alpha = scal[iter] / (scal[16+iter] + 1e-12f);
    int gid = blockIdx.x*blockDim.x + threadIdx.x;
    int gsz = gridDim.x*blockDim.x;
    float rs = 0.f;
    const int NV = NS*HW;
    for (int i = gid; i < NV; i += gsz){
        float2 a0=part[i], a1=part[NV+i], a2=part[2*NV+i], a3=part[3*NV+i];
        float2 pvv=p[i], xv=x[i], rv=r[i];
        float2 av = make_float2(a0.x+a1.x+a2.x+a3.x + RHO_*pvv.x,
                                a0.y+a1.y+a2.y+a3.y + RHO_*pvv.y);
        xv.x += alpha*pvv.x; xv.y += alpha*pvv.y;
        rv.x -= alpha*av.x;  rv.y -= alpha*av.y;
        x[i]=xv; r[i]=rv;
        rs += rv.x*rv.x + rv.y*rv.y;
    }
    red[threadIdx.x]=rs; __syncthreads();
    for (int o=128;o>0;o>>=1){ if (threadIdx.x<o) red[threadIdx.x]+=red[threadIdx.x+o]; __syncthreads(); }
    if (threadIdx.x==0) atomicAdd(&scal[iter+1], red[0]);
}

__global__ void k_final(const float2* __restrict__ x, float2* __restrict__ out)
{
    int gid = blockIdx.x*blockDim.x + threadIdx.x;
    int gsz = gridDim.x*blockDim.x;
    for (int i = gid; i < NS*HW; i += gsz){
        int w = i % NDIM; int h = (i/NDIM)%NDIM; int s = i/HW;
        out[i] = x[(long)s*HW + sh160(h)*NDIM + sh160(w)];
    }
}

extern "C" void kernel_launch(void* const* d_in, const int* in_sizes, int n_in,
                              void* d_out, int out_size, void* d_ws, size_t ws_size,
                              hipStream_t stream) {
    (void)in_sizes; (void)n_in; (void)out_size; (void)ws_size;
    const float2* kin  = (const float2*)d_in[0];
    const float2* Iin  = (const float2*)d_in[1];
    const float2* csm  = (const float2*)d_in[2];
    const float*  mask = (const float*)d_in[3];

    char* w = (char*)d_ws;
    size_t off = 0;
    float*  scal = (float*)(w+off);  off += 1024;
    float2* sP   = (float2*)(w+off); off += (size_t)NC*HW*8;
    float*  mscT = (float*)(w+off);  off += (size_t)NS*HW*4;
    float2* K    = (float2*)(w+off); off += (size_t)NS*NC*HW*8;
    float2* x    = (float2*)(w+off); off += (size_t)NS*HW*8;
    float2* r    = (float2*)(w+off); off += (size_t)NS*HW*8;
    float2* pA   = (float2*)(w+off); off += (size_t)NS*HW*8;
    float2* pB   = (float2*)(w+off); off += (size_t)NS*HW*8;
    float2* part = (float2*)(w+off); off += (size_t)4*NS*HW*8;

    k_prep<<<2048,256,0,stream>>>(kin, mask, csm, sP, mscT, K, scal);
    k_passB<<<NS*NC*80,256,0,stream>>>(K, mscT, 0);
    k_passC2<<<NS*80*4,256,0,stream>>>(K, sP, r, part, scal, 63, 0);
    k_rhs_fin<<<640,256,0,stream>>>(part, Iin, r, x, scal);

    for (int it=0; it<CG_ITERS; ++it){
        float2* pNew = (it&1)? pB : pA;
        float2* pOld = (it&1)? pA : pB;
        k_passA<<<NS*80*4,256,0,stream>>>(r, pOld, pNew, sP, K, scal, it);
        k_passB<<<NS*NC*80,256,0,stream>>>(K, mscT, 1);
        k_passC2<<<NS*80*4,256,0,stream>>>(K, sP, pNew, part, scal, 16+it, 1);
        k_update<<<640,256,0,stream>>>(x, r, pNew, part, scal, it);
    }
    k_final<<<512,256,0,stream>>>(x, (float2*)d_out);
}

// Round 5
// 1824.398 us; speedup vs baseline: 1.1479x; 1.1479x over previous
//
#include <hip/hip_runtime.h>
#include <math.h>

// ---------------------------------------------------------------------------
// SENSE CG reconstruction, B=1, S=4, C=16, H=W=320, rho=0.1, 15 CG iters.
// Conjugated by fftshift (even N): CG loop uses plain FFTs; final
// ifft2c(fft2c(x)) == x skipped. FFT-320 = Stockham 5*4*4*4, one wave per
// line, IN-PLACE per stage (read-phase / wave-fence / write-phase; safe
// because a wave executes in lockstep and DS ops are in-order per wave).
// R5: in-place FFT halves LDS -> passB 8col/512thr @20.7KB (32 waves/CU,
//     was 24), passA/C2 @10.2KB. R4 post-mortem: 4-col tile doubled
//     FETCH_SIZE (32B chunks split cache lines across blocks) -> reverted.
// ---------------------------------------------------------------------------

#define NDIM 320
#define HHALF 160
#define HW (NDIM*NDIM)
#define NS 4
#define NC 16
#define RHO_ 0.1f
#define CG_ITERS 15

__device__ __forceinline__ void wsync(){
    __builtin_amdgcn_fence(__ATOMIC_ACQ_REL, "wavefront");
    __builtin_amdgcn_wave_barrier();
}

__device__ __forceinline__ float wred(float v){
    #pragma unroll
    for (int o=32;o>0;o>>=1) v += __shfl_down(v,o,64);
    return v;  // valid on lane 0
}

__device__ __forceinline__ float2 cmulf(float2 a, float2 b){
    return make_float2(a.x*b.x - a.y*b.y, a.x*b.y + a.y*b.x);
}

template<int SIGMA>
__device__ __forceinline__ float2 cmulw(float2 a, float2 w){
    float wy = (SIGMA < 0) ? w.y : -w.y;
    return make_float2(a.x*w.x - a.y*wy, a.x*wy + a.y*w.x);
}

template<int SIGMA>
__device__ __forceinline__ void radix4(const float2* u, float2* v){
    float2 a = make_float2(u[0].x+u[2].x, u[0].y+u[2].y);
    float2 b = make_float2(u[0].x-u[2].x, u[0].y-u[2].y);
    float2 c = make_float2(u[1].x+u[3].x, u[1].y+u[3].y);
    float2 d = make_float2(u[1].x-u[3].x, u[1].y-u[3].y);
    float2 jd = make_float2(-(float)SIGMA*d.y, (float)SIGMA*d.x);
    v[0] = make_float2(a.x+c.x, a.y+c.y);
    v[1] = make_float2(b.x+jd.x, b.y+jd.y);
    v[2] = make_float2(a.x-c.x, a.y-c.y);
    v[3] = make_float2(b.x-jd.x, b.y-jd.y);
}

template<int SIGMA>
__device__ __forceinline__ void radix5(const float2* u, float2* v){
    const float C1 = 0.30901699437494742f, S1 = 0.95105651629515357f;
    const float C2 = -0.80901699437494745f, S2 = 0.58778525229247312f;
    float2 t1 = make_float2(u[1].x+u[4].x, u[1].y+u[4].y);
    float2 t2 = make_float2(u[2].x+u[3].x, u[2].y+u[3].y);
    float2 t3 = make_float2(u[1].x-u[4].x, u[1].y-u[4].y);
    float2 t4 = make_float2(u[2].x-u[3].x, u[2].y-u[3].y);
    v[0] = make_float2(u[0].x + t1.x + t2.x, u[0].y + t1.y + t2.y);
    float2 m1 = make_float2(u[0].x + C1*t1.x + C2*t2.x, u[0].y + C1*t1.y + C2*t2.y);
    float2 m2 = make_float2(u[0].x + C2*t1.x + C1*t2.x, u[0].y + C2*t1.y + C1*t2.y);
    float2 n1 = make_float2(S1*t3.x + S2*t4.x, S1*t3.y + S2*t4.y);
    float2 n2 = make_float2(S2*t3.x - S1*t4.x, S2*t3.y - S1*t4.y);
    float2 j1 = make_float2(-(float)SIGMA*n1.y, (float)SIGMA*n1.x);
    float2 j2 = make_float2(-(float)SIGMA*n2.y, (float)SIGMA*n2.x);
    v[1] = make_float2(m1.x + j1.x, m1.y + j1.y);
    v[4] = make_float2(m1.x - j1.x, m1.y - j1.y);
    v[2] = make_float2(m2.x + j2.x, m2.y + j2.y);
    v[3] = make_float2(m2.x - j2.x, m2.y - j2.y);
}

struct Tw { float2 w20a, w20b, w80a, w80b, w320a, w320b; };

__device__ __forceinline__ Tw make_tw(int t){
    Tw tw; float sn, cs;
    const float n2pi = -6.283185307179586f;
    __sincosf(n2pi*(float)(t%5)    /20.f,  &sn,&cs); tw.w20a = make_float2(cs,sn);
    __sincosf(n2pi*(float)((t+4)%5)/20.f,  &sn,&cs); tw.w20b = make_float2(cs,sn);
    __sincosf(n2pi*(float)(t%20)    /80.f, &sn,&cs); tw.w80a = make_float2(cs,sn);
    __sincosf(n2pi*(float)((t+4)%20)/80.f, &sn,&cs); tw.w80b = make_float2(cs,sn);
    __sincosf(n2pi*(float)t      /320.f,   &sn,&cs); tw.w320a= make_float2(cs,sn);
    __sincosf(n2pi*(float)(t+64) /320.f,   &sn,&cs); tw.w320b= make_float2(cs,sn);
    return tw;
}

// twiddle + radix4 + in-place write for butterfly i, stage P.
template<int SIGMA, int P>
__device__ __forceinline__ void s4_cw(float2* __restrict__ A, int i,
                                      float2* u, float2 w1){
    float2 w2 = cmulf(w1,w1);
    float2 w3 = cmulf(w2,w1);
    u[1] = cmulw<SIGMA>(u[1], w1);
    u[2] = cmulw<SIGMA>(u[2], w2);
    u[3] = cmulw<SIGMA>(u[3], w3);
    float2 v[4];
    radix4<SIGMA>(u,v);
    int k = i % P, jb = i / P;
    int base = jb*(4*P) + k;
    #pragma unroll
    for (int c=0;c<4;++c) A[base + c*P] = v[c];
}

// In-place radix-4 stage: read ALL inputs (both butterflies), fence, write.
template<int SIGMA, int P>
__device__ __forceinline__ void stage4ip(float2* __restrict__ A, int t,
                                         float2 wa, float2 wb){
    float2 a[4], b[4];
    #pragma unroll
    for (int q=0;q<4;++q) a[q] = A[t + 80*q];
    bool tb = (t<16);
    if (tb){
        #pragma unroll
        for (int q=0;q<4;++q) b[q] = A[t+64 + 80*q];
    }
    wsync();                       // all wave reads precede any write
    s4_cw<SIGMA,P>(A, t, a, wa);
    if (tb) s4_cw<SIGMA,P>(A, t+64, b, wb);
}

// 320-pt FFT in place over A (wave-local line).
template<int SIGMA>
__device__ __forceinline__ void fft320ip(float2* __restrict__ A,
                                         int t, const Tw& tw){
    // stage 1: radix-5, T=64 (exactly one butterfly per lane)
    float2 u[5];
    #pragma unroll
    for (int q=0;q<5;++q) u[q] = A[t + 64*q];
    wsync();
    {
        float2 v[5];
        radix5<SIGMA>(u,v);
        #pragma unroll
        for (int c=0;c<5;++c) A[5*t + c] = v[c];
    }
    wsync();
    stage4ip<SIGMA,5 >(A, t, tw.w20a,  tw.w20b);
    wsync();
    stage4ip<SIGMA,20>(A, t, tw.w80a,  tw.w80b);
    wsync();
    stage4ip<SIGMA,80>(A, t, tw.w320a, tw.w320b);
    wsync();
}

__device__ __forceinline__ int sh160(int i){ return i < HHALF ? i + HHALF : i - HHALF; }

// ---------------------------------------------------------------------------
__global__ void k_prep(const float2* __restrict__ kin, const float* __restrict__ mask,
                       const float2* __restrict__ csm, float2* __restrict__ sP,
                       float* __restrict__ mscT, float2* __restrict__ K,
                       float* __restrict__ scal)
{
    int gid = blockIdx.x*blockDim.x + threadIdx.x;
    int gsz = gridDim.x*blockDim.x;
    if (gid < 64) scal[gid] = 0.f;
    for (int i = gid; i < NC*HW; i += gsz){
        int w = i % NDIM; int h = (i/NDIM) % NDIM; int c = i/HW;
        sP[i] = csm[(c*NDIM + sh160(h))*NDIM + sh160(w)];
    }
    for (int i = gid; i < NS*HW; i += gsz){
        int h = i % NDIM; int wc = (i/NDIM)%NDIM; int s = i/HW;
        float m = mask[(s*NDIM + sh160(h))*NDIM + sh160(wc)];
        mscT[i] = m*m*(1.0f/102400.0f);
    }
    for (int i = gid; i < NS*NC*HW; i += gsz){
        int w = i % NDIM; int h = (i/NDIM)%NDIM; int sc = i/HW;
        int s = sc >> 4;
        int hs = sh160(h), ws = sh160(w);
        float m = mask[(s*NDIM + hs)*NDIM + ws];
        float2 kv = kin[((long)sc*NDIM + hs)*NDIM + ws];
        float f = m*(1.0f/320.0f);
        K[i] = make_float2(kv.x*f, kv.y*f);
    }
}

// ---------------------------------------------------------------------------
// PassA: p = r + beta*p fused; K[s,c,h,:] = rowFFT(s'_c .* p).
// grid = S*80*4 ; 256 thr = 4 waves, one row per wave. LDS 10.2KB.
__global__ __launch_bounds__(256) void k_passA(
    const float2* __restrict__ rv_, const float2* __restrict__ pOld,
    float2* __restrict__ pNew, const float2* __restrict__ sP,
    float2* __restrict__ K, float* __restrict__ scal, int iter)
{
    int bid = blockIdx.x;
    int cg = bid & 3;
    int hg = (bid>>2) % 80;
    int s  = bid / (4*80);
    int tid = threadIdx.x; int rl = tid>>6; int t = tid&63;
    int h = hg*4 + rl;
    __shared__ float2 bufA[4][NDIM];
    float2* A = &bufA[rl][0];
    Tw tw = make_tw(t);
    float beta = 0.f;
    if (iter > 0) beta = scal[iter] / (scal[iter-1] + 1e-12f);
    long base = (long)s*HW + h*NDIM;
    float2 pv[5];
    #pragma unroll
    for (int j=0;j<5;++j){
        int idx = t + 64*j;
        float2 rr = rv_[base+idx];
        if (iter > 0){
            float2 pp = pOld[base+idx];
            pv[j] = make_float2(rr.x + beta*pp.x, rr.y + beta*pp.y);
        } else pv[j] = rr;
    }
    if (cg == 0){
        float d = 0.f;
        #pragma unroll
        for (int j=0;j<5;++j){
            pNew[base + t + 64*j] = pv[j];
            d += pv[j].x*pv[j].x + pv[j].y*pv[j].y;
        }
        float wd = wred(d);
        if (t==0) atomicAdd(&scal[16+iter], RHO_*wd);
    }
    int c = cg*4;
    const float2* srow = sP + (long)c*HW + h*NDIM;
    float2 sv[5];
    #pragma unroll
    for (int j=0;j<5;++j) sv[j] = srow[t+64*j];
    #pragma unroll
    for (int c0=0;c0<4;++c0){
        #pragma unroll
        for (int j=0;j<5;++j) A[t+64*j] = cmulf(sv[j], pv[j]);   // lane-local
        float2 sv2[5];
        if (c0<3){
            const float2* sr2 = srow + (long)(c0+1)*HW;
            #pragma unroll
            for (int j=0;j<5;++j) sv2[j] = sr2[t+64*j];
        }
        fft320ip<-1>(A,t,tw);
        long kb = ((long)(s*NC + c + c0))*HW + h*NDIM;
        #pragma unroll
        for (int j=0;j<5;++j){ int idx=t+64*j; K[kb+idx] = A[idx]; }
        wsync();
        if (c0<3){
            #pragma unroll
            for (int j=0;j<5;++j) sv[j]=sv2[j];
        }
    }
}

// ---------------------------------------------------------------------------
// PassB: per (s,c) image, 8-column LDS tile (64B-chunk coalesced loads):
// colFFT -> mask*scale -> colIFFT (doMask=1) or colIFFT only. In-place on K.
// 512 thr = 8 waves, one column per wave; LDS 20.7KB -> 32 waves/CU.
__global__ __launch_bounds__(512) void k_passB(float2* __restrict__ K,
    const float* __restrict__ mscT, int doMask)
{
    constexpr int L = 324;
    int bid = blockIdx.x;
    int wt = bid % 40;
    int sc = bid / 40;
    int s = sc >> 4;
    int tid = threadIdx.x;
    int col = tid >> 6;
    int t = tid & 63;
    int w0 = wt*8;
    __shared__ float2 bufA[8][L];
    Tw tw = make_tw(t);
    float mv[5];
    if (doMask){
        const float* mcol = mscT + (long)s*HW + (long)(w0+col)*NDIM;
        #pragma unroll
        for (int j=0;j<5;++j) mv[j] = mcol[t+64*j];
    }
    long gb = (long)sc*HW;
    int wl = tid & 7, hb = tid >> 3;  // 64B contiguous per 8 lanes
    #pragma unroll
    for (int j=0;j<5;++j){
        int hh = hb + 64*j;
        bufA[wl][hh] = K[gb + (long)hh*NDIM + w0 + wl];
    }
    __syncthreads();
    float2* A = &bufA[col][0];
    if (doMask){
        fft320ip<-1>(A,t,tw);
        #pragma unroll
        for (int j=0;j<5;++j){
            int hh = t + 64*j;
            A[hh].x *= mv[j]; A[hh].y *= mv[j];
        }
        fft320ip<1>(A,t,tw);
    } else {
        fft320ip<1>(A,t,tw);
    }
    __syncthreads();
    #pragma unroll
    for (int j=0;j<5;++j){
        int hh = hb + 64*j;
        K[gb + (long)hh*NDIM + w0 + wl] = bufA[wl][hh];
    }
}

// ---------------------------------------------------------------------------
// PassC2: rowIFFT of one coil-group (4 coils), conj(s')-combine into
// part[cg]; optional partial p.part dot into scal[dotSlot]. LDS 10.2KB.
__global__ __launch_bounds__(256) void k_passC2(
    const float2* __restrict__ K, const float2* __restrict__ sP,
    const float2* __restrict__ pVec, float2* __restrict__ part,
    float* __restrict__ scal, int dotSlot, int doDot)
{
    int bid = blockIdx.x;
    int cg = bid & 3;
    int hg = (bid>>2) % 80;
    int s  = bid / (4*80);
    int tid = threadIdx.x; int rl = tid>>6; int t = tid&63;
    int h = hg*4 + rl;
    __shared__ float2 bufA[4][NDIM];
    __shared__ float redS[4];
    float2* A = &bufA[rl][0];
    Tw tw = make_tw(t);
    int c = cg*4;
    long kb0 = ((long)(s*NC + c))*HW + h*NDIM;
    const float2* srow = sP + (long)c*HW + h*NDIM;
    float2 kv[5], sv[5];
    #pragma unroll
    for (int j=0;j<5;++j){ int idx=t+64*j; kv[j]=K[kb0+idx]; sv[j]=srow[idx]; }
    float2 acc[5];
    #pragma unroll
    for (int j=0;j<5;++j) acc[j]=make_float2(0.f,0.f);
    #pragma unroll
    for (int c0=0;c0<4;++c0){
        #pragma unroll
        for (int j=0;j<5;++j) A[t+64*j] = kv[j];   // lane-local
        float2 kv2[5], sv2[5];
        if (c0<3){
            long kb = kb0 + (long)(c0+1)*HW;
            const float2* sr2 = srow + (long)(c0+1)*HW;
            #pragma unroll
            for (int j=0;j<5;++j){ int idx=t+64*j; kv2[j]=K[kb+idx]; sv2[j]=sr2[idx]; }
        }
        fft320ip<1>(A,t,tw);
        #pragma unroll
        for (int j=0;j<5;++j){
            float2 uv = A[t+64*j];
            acc[j].x += sv[j].x*uv.x + sv[j].y*uv.y;
            acc[j].y += sv[j].x*uv.y - sv[j].y*uv.x;
        }
        wsync();
        if (c0<3){
            #pragma unroll
            for (int j=0;j<5;++j){ kv[j]=kv2[j]; sv[j]=sv2[j]; }
        }
    }
    long pbase = (long)s*HW + h*NDIM;
    long obase = ((long)cg*NS + s)*HW + h*NDIM;
    float dot = 0.f;
    #pragma unroll
    for (int j=0;j<5;++j){
        int idx=t+64*j;
        part[obase+idx] = acc[j];
        if (doDot){
            float2 pp = pVec[pbase+idx];
            dot += pp.x*acc[j].x + pp.y*acc[j].y;
        }
    }
    if (doDot){
        float wd = wred(dot);
        if (t==0) redS[rl] = wd;
        __syncthreads();
        if (tid==0) atomicAdd(&scal[dotSlot], redS[0]+redS[1]+redS[2]+redS[3]);
    }
}

// ---------------------------------------------------------------------------
__global__ __launch_bounds__(256) void k_rhs_fin(
    const float2* __restrict__ part, const float2* __restrict__ Iin,
    float2* __restrict__ r, float2* __restrict__ x, float* __restrict__ scal)
{
    __shared__ float red[256];
    int gid = blockIdx.x*blockDim.x + threadIdx.x;
    int gsz = gridDim.x*blockDim.x;
    float rs = 0.f;
    const int NV = NS*HW;
    for (int i = gid; i < NV; i += gsz){
        int w = i % NDIM; int h = (i/NDIM)%NDIM; int s = i/HW;
        float2 iv = Iin[((long)s*NDIM + sh160(h))*NDIM + sh160(w)];
        float2 a0=part[i], a1=part[NV+i], a2=part[2*NV+i], a3=part[3*NV+i];
        float2 rr = make_float2(a0.x+a1.x+a2.x+a3.x + RHO_*iv.x,
                                a0.y+a1.y+a2.y+a3.y + RHO_*iv.y);
        r[i] = rr;
        x[i] = make_float2(0.f,0.f);
        rs += rr.x*rr.x + rr.y*rr.y;
    }
    red[threadIdx.x]=rs; __syncthreads();
    for (int o=128;o>0;o>>=1){ if (threadIdx.x<o) red[threadIdx.x]+=red[threadIdx.x+o]; __syncthreads(); }
    if (threadIdx.x==0) atomicAdd(&scal[0], red[0]);
}

// ---------------------------------------------------------------------------
__global__ __launch_bounds__(256) void k_update(
    float2* __restrict__ x, float2* __restrict__ r,
    const float2* __restrict__ p, const float2* __restrict__ part,
    float* __restrict__ scal, int iter)
{
    __shared__ float red[256];
    float alpha = scal[iter] / (scal[16+iter] + 1e-12f);
    int gid = blockIdx.x*blockDim.x + threadIdx.x;
    int gsz = gridDim.x*blockDim.x;
    float rs = 0.f;
    const int NV = NS*HW;
    for (int i = gid; i < NV; i += gsz){
        float2 a0=part[i], a1=part[NV+i], a2=part[2*NV+i], a3=part[3*NV+i];
        float2 pvv=p[i], xv=x[i], rv=r[i];
        float2 av = make_float2(a0.x+a1.x+a2.x+a3.x + RHO_*pvv.x,
                                a0.y+a1.y+a2.y+a3.y + RHO_*pvv.y);
        xv.x += alpha*pvv.x; xv.y += alpha*pvv.y;
        rv.x -= alpha*av.x;  rv.y -= alpha*av.y;
        x[i]=xv; r[i]=rv;
        rs += rv.x*rv.x + rv.y*rv.y;
    }
    red[threadIdx.x]=rs; __syncthreads();
    for (int o=128;o>0;o>>=1){ if (threadIdx.x<o) red[threadIdx.x]+=red[threadIdx.x+o]; __syncthreads(); }
    if (threadIdx.x==0) atomicAdd(&scal[iter+1], red[0]);
}

__global__ void k_final(const float2* __restrict__ x, float2* __restrict__ out)
{
    int gid = blockIdx.x*blockDim.x + threadIdx.x;
    int gsz = gridDim.x*blockDim.x;
    for (int i = gid; i < NS*HW; i += gsz){
        int w = i % NDIM; int h = (i/NDIM)%NDIM; int s = i/HW;
        out[i] = x[(long)s*HW + sh160(h)*NDIM + sh160(w)];
    }
}

extern "C" void kernel_launch(void* const* d_in, const int* in_sizes, int n_in,
                              void* d_out, int out_size, void* d_ws, size_t ws_size,
                              hipStream_t stream) {
    (void)in_sizes; (void)n_in; (void)out_size; (void)ws_size;
    const float2* kin  = (const float2*)d_in[0];
    const float2* Iin  = (const float2*)d_in[1];
    const float2* csm  = (const float2*)d_in[2];
    const float*  mask = (const float*)d_in[3];

    char* w = (char*)d_ws;
    size_t off = 0;
    float*  scal = (float*)(w+off);  off += 1024;
    float2* sP   = (float2*)(w+off); off += (size_t)NC*HW*8;
    float*  mscT = (float*)(w+off);  off += (size_t)NS*HW*4;
    float2* K    = (float2*)(w+off); off += (size_t)NS*NC*HW*8;
    float2* x    = (float2*)(w+off); off += (size_t)NS*HW*8;
    float2* r    = (float2*)(w+off); off += (size_t)NS*HW*8;
    float2* pA   = (float2*)(w+off); off += (size_t)NS*HW*8;
    float2* pB   = (float2*)(w+off); off += (size_t)NS*HW*8;
    float2* part = (float2*)(w+off); off += (size_t)4*NS*HW*8;

    k_prep<<<2048,256,0,stream>>>(kin, mask, csm, sP, mscT, K, scal);
    k_passB<<<NS*NC*40,512,0,stream>>>(K, mscT, 0);
    k_passC2<<<NS*80*4,256,0,stream>>>(K, sP, r, part, scal, 63, 0);
    k_rhs_fin<<<640,256,0,stream>>>(part, Iin, r, x, scal);

    for (int it=0; it<CG_ITERS; ++it){
        float2* pNew = (it&1)? pB : pA;
        float2* pOld = (it&1)? pA : pB;
        k_passA<<<NS*80*4,256,0,stream>>>(r, pOld, pNew, sP, K, scal, it);
        k_passB<<<NS*NC*40,512,0,stream>>>(K, mscT, 1);
        k_passC2<<<NS*80*4,256,0,stream>>>(K, sP, pNew, part, scal, 16+it, 1);
        k_update<<<640,256,0,stream>>>(x, r, pNew, part, scal, it);
    }
    k_final<<<512,256,0,stream>>>(x, (float2*)d_out);
}

// Round 6
// 1679.923 us; speedup vs baseline: 1.2466x; 1.0860x over previous
//
#include <hip/hip_runtime.h>
#include <math.h>

// ---------------------------------------------------------------------------
// SENSE CG reconstruction, B=1, S=4, C=16, H=W=320, rho=0.1, 15 CG iters.
// Conjugated by fftshift (even N): CG loop uses plain FFTs; final
// ifft2c(fft2c(x)) == x skipped.
// R6: FFT-320 = Stockham {5,8,8} (was {5,4,4,4}); stage1 radix-5 in
//     registers; stage3 direct to/from global (natural order preserved);
//     inverse implemented as the ADJOINT network (reversed stages, conj
//     twiddles) so it consumes stage-3 register layout directly.
//     DS-b64 ops/element: passA/C 10->4, passB 20->12.
//     R5 evidence: FFT kernels are LDS-pipe throughput bound (occupancy
//     levers x2 did nothing; DS-cycle model matches measured 56us).
// ---------------------------------------------------------------------------

#define NDIM 320
#define HHALF 160
#define HW (NDIM*NDIM)
#define NS 4
#define NC 16
#define RHO_ 0.1f
#define CG_ITERS 15

__device__ __forceinline__ void wsync(){
    __builtin_amdgcn_fence(__ATOMIC_ACQ_REL, "wavefront");
    __builtin_amdgcn_wave_barrier();
}

__device__ __forceinline__ float wred(float v){
    #pragma unroll
    for (int o=32;o>0;o>>=1) v += __shfl_down(v,o,64);
    return v;  // valid on lane 0
}

__device__ __forceinline__ float2 cmulf(float2 a, float2 b){
    return make_float2(a.x*b.x - a.y*b.y, a.x*b.y + a.y*b.x);
}

// multiply by stored forward twiddle (SIGMA=-1) or its conjugate (SIGMA=+1)
template<int SIGMA>
__device__ __forceinline__ float2 cmulw(float2 a, float2 w){
    float wy = (SIGMA < 0) ? w.y : -w.y;
    return make_float2(a.x*w.x - a.y*wy, a.x*wy + a.y*w.x);
}

__device__ __forceinline__ float2 cadd(float2 a,float2 b){return make_float2(a.x+b.x,a.y+b.y);}
__device__ __forceinline__ float2 csub(float2 a,float2 b){return make_float2(a.x-b.x,a.y-b.y);}

template<int SIGMA>
__device__ __forceinline__ float2 mulj(float2 z){  // SIGMA*i*z
    return make_float2(-(float)SIGMA*z.y, (float)SIGMA*z.x);
}

template<int SIGMA>
__device__ __forceinline__ void radix5(const float2* u, float2* v){
    const float C1 = 0.30901699437494742f, S1 = 0.95105651629515357f;
    const float C2 = -0.80901699437494745f, S2 = 0.58778525229247312f;
    float2 t1 = cadd(u[1],u[4]), t2 = cadd(u[2],u[3]);
    float2 t3 = csub(u[1],u[4]), t4 = csub(u[2],u[3]);
    v[0] = make_float2(u[0].x + t1.x + t2.x, u[0].y + t1.y + t2.y);
    float2 m1 = make_float2(u[0].x + C1*t1.x + C2*t2.x, u[0].y + C1*t1.y + C2*t2.y);
    float2 m2 = make_float2(u[0].x + C2*t1.x + C1*t2.x, u[0].y + C2*t1.y + C1*t2.y);
    float2 n1 = make_float2(S1*t3.x + S2*t4.x, S1*t3.y + S2*t4.y);
    float2 n2 = make_float2(S2*t3.x - S1*t4.x, S2*t3.y - S1*t4.y);
    float2 j1 = mulj<SIGMA>(n1);
    float2 j2 = mulj<SIGMA>(n2);
    v[1] = cadd(m1,j1); v[4] = csub(m1,j1);
    v[2] = cadd(m2,j2); v[3] = csub(m2,j2);
}

template<int SIGMA>
__device__ __forceinline__ void dft8(const float2* u, float2* y){
    const float C = 0.70710678118654752f;
    const float s = (float)SIGMA;
    float2 a0=cadd(u[0],u[4]), a1=csub(u[0],u[4]);
    float2 a2=cadd(u[2],u[6]), a3=csub(u[2],u[6]);
    float2 a4=cadd(u[1],u[5]), a5=csub(u[1],u[5]);
    float2 a6=cadd(u[3],u[7]), a7=csub(u[3],u[7]);
    float2 j3 = mulj<SIGMA>(a3);
    float2 E0=cadd(a0,a2), E2=csub(a0,a2);
    float2 E1=cadd(a1,j3), E3=csub(a1,j3);
    float2 j7 = mulj<SIGMA>(a7);
    float2 O0=cadd(a4,a6), O2=csub(a4,a6);
    float2 O1=cadd(a5,j7), O3=csub(a5,j7);
    float2 W1 = make_float2(C*(O1.x - s*O1.y), C*(s*O1.x + O1.y));   // w^1*O1
    float2 jO2 = mulj<SIGMA>(O2);                                     // w^2*O2
    float2 W3 = make_float2(C*(-O3.x - s*O3.y), C*(s*O3.x - O3.y));  // w^3*O3
    y[0]=cadd(E0,O0); y[4]=csub(E0,O0);
    y[1]=cadd(E1,W1); y[5]=csub(E1,W1);
    y[2]=cadd(E2,jO2); y[6]=csub(E2,jO2);
    y[3]=cadd(E3,W3); y[7]=csub(E3,W3);
}

// ---- forward Stockham {5,8,8}: natural in -> natural out -------------------
// S1: butterfly t: in x[t+64q] -> out A[5t+c].
template<int SIGMA>
__device__ __forceinline__ void s1_from_regs(float2* __restrict__ A, int t,
                                             const float2* u5){
    float2 v[5];
    radix5<SIGMA>(u5, v);
    #pragma unroll
    for (int c=0;c<5;++c) A[5*t + c] = v[c];
}

template<int SIGMA>
__device__ __forceinline__ void s1_stage(float2* __restrict__ A, int t){
    float2 u[5];
    #pragma unroll
    for (int q=0;q<5;++q) u[q] = A[t + 64*q];
    wsync();
    s1_from_regs<SIGMA>(A, t, u);
}

// S2: P=5. butterfly i=t<40: read A[t+40q], twiddle W_40^{q*(t%5)}, dft8,
//     write A[(t/5)*40 + t%5 + 5c].
template<int SIGMA>
__device__ __forceinline__ void s2_stage(float2* __restrict__ A, int t, float2 w40){
    if (t < 40){
        float2 u[8];
        #pragma unroll
        for (int q=0;q<8;++q) u[q] = A[t + 40*q];
        wsync();
        float2 wc = w40;
        u[1] = cmulw<SIGMA>(u[1], wc);
        #pragma unroll
        for (int q=2;q<8;++q){ wc = cmulf(wc, w40); u[q] = cmulw<SIGMA>(u[q], wc); }
        float2 v[8];
        dft8<SIGMA>(u, v);
        int k = t % 5, jb = t / 5;
        int base = jb*40 + k;
        #pragma unroll
        for (int c=0;c<8;++c) A[base + 5*c] = v[c];
    }
}

// S3: P=40. butterfly i=t<40: read A[t+40q], twiddle W_320^{q*t}, dft8 ->
//     v[c] = X[t+40c] (registers; caller stores).
template<int SIGMA>
__device__ __forceinline__ void s3_toregs(const float2* __restrict__ A, int t,
                                          float2 w320, float2* v){
    if (t < 40){
        float2 u[8];
        #pragma unroll
        for (int q=0;q<8;++q) u[q] = A[t + 40*q];
        float2 wc = w320;
        u[1] = cmulw<SIGMA>(u[1], wc);
        #pragma unroll
        for (int q=2;q<8;++q){ wc = cmulf(wc, w320); u[q] = cmulw<SIGMA>(u[q], wc); }
        dft8<SIGMA>(u, v);
    }
}

// ---- adjoint network (unnormalized inverse), X[t+40c] regs -> natural -----
template<int SIGMA>
__device__ __forceinline__ void a3_fromregs(float2* __restrict__ A, int t,
                                            float2 w320, const float2* vin){
    if (t < 40){
        float2 u[8];
        dft8<SIGMA>(vin, u);
        float2 wc = w320;
        u[1] = cmulw<SIGMA>(u[1], wc);
        #pragma unroll
        for (int q=2;q<8;++q){ wc = cmulf(wc, w320); u[q] = cmulw<SIGMA>(u[q], wc); }
        #pragma unroll
        for (int q=0;q<8;++q) A[t + 40*q] = u[q];
    }
}

template<int SIGMA>
__device__ __forceinline__ void a2_stage(float2* __restrict__ A, int t, float2 w40){
    if (t < 40){
        int k = t % 5, jb = t / 5;
        int base = jb*40 + k;
        float2 v[8];
        #pragma unroll
        for (int c=0;c<8;++c) v[c] = A[base + 5*c];
        wsync();
        float2 u[8];
        dft8<SIGMA>(v, u);
        float2 wc = w40;
        u[1] = cmulw<SIGMA>(u[1], wc);
        #pragma unroll
        for (int q=2;q<8;++q){ wc = cmulf(wc, w40); u[q] = cmulw<SIGMA>(u[q], wc); }
        #pragma unroll
        for (int q=0;q<8;++q) A[t + 40*q] = u[q];
    }
}

template<int SIGMA>
__device__ __forceinline__ void a1_toregs(const float2* __restrict__ A, int t,
                                          float2* out5){
    float2 v[5];
    #pragma unroll
    for (int c=0;c<5;++c) v[c] = A[5*t + c];
    radix5<SIGMA>(v, out5);
}

__device__ __forceinline__ void make_w(int t, float2& w40, float2& w320){
    float sn, cs;
    const float n2pi = -6.283185307179586f;
    __sincosf(n2pi*(float)(t%5)/40.f, &sn, &cs); w40  = make_float2(cs, sn);
    __sincosf(n2pi*(float)t/320.f,    &sn, &cs); w320 = make_float2(cs, sn);
}

__device__ __forceinline__ int sh160(int i){ return i < HHALF ? i + HHALF : i - HHALF; }

// ---------------------------------------------------------------------------
__global__ void k_prep(const float2* __restrict__ kin, const float* __restrict__ mask,
                       const float2* __restrict__ csm, float2* __restrict__ sP,
                       float* __restrict__ mscT, float2* __restrict__ K,
                       float* __restrict__ scal)
{
    int gid = blockIdx.x*blockDim.x + threadIdx.x;
    int gsz = gridDim.x*blockDim.x;
    if (gid < 64) scal[gid] = 0.f;
    for (int i = gid; i < NC*HW; i += gsz){
        int w = i % NDIM; int h = (i/NDIM) % NDIM; int c = i/HW;
        sP[i] = csm[(c*NDIM + sh160(h))*NDIM + sh160(w)];
    }
    for (int i = gid; i < NS*HW; i += gsz){
        int h = i % NDIM; int wc = (i/NDIM)%NDIM; int s = i/HW;
        float m = mask[(s*NDIM + sh160(h))*NDIM + sh160(wc)];
        mscT[i] = m*m*(1.0f/102400.0f);
    }
    for (int i = gid; i < NS*NC*HW; i += gsz){
        int w = i % NDIM; int h = (i/NDIM)%NDIM; int sc = i/HW;
        int s = sc >> 4;
        int hs = sh160(h), ws = sh160(w);
        float m = mask[(s*NDIM + hs)*NDIM + ws];
        float2 kv = kin[((long)sc*NDIM + hs)*NDIM + ws];
        float f = m*(1.0f/320.0f);
        K[i] = make_float2(kv.x*f, kv.y*f);
    }
}

// ---------------------------------------------------------------------------
// PassA: p = r + beta*p fused; K[s,c,h,:] = rowFFT(s'_c .* p).
// grid = S*80*4 ; 256 thr = 4 waves, one row per wave. LDS 10.2KB.
__global__ __launch_bounds__(256) void k_passA(
    const float2* __restrict__ rv_, const float2* __restrict__ pOld,
    float2* __restrict__ pNew, const float2* __restrict__ sP,
    float2* __restrict__ K, float* __restrict__ scal, int iter)
{
    int bid = blockIdx.x;
    int cg = bid & 3;
    int hg = (bid>>2) % 80;
    int s  = bid / (4*80);
    int tid = threadIdx.x; int rl = tid>>6; int t = tid&63;
    int h = hg*4 + rl;
    __shared__ float2 bufA[4][NDIM];
    float2* A = &bufA[rl][0];
    float2 w40, w320; make_w(t, w40, w320);
    float beta = 0.f;
    if (iter > 0) beta = scal[iter] / (scal[iter-1] + 1e-12f);
    long base = (long)s*HW + h*NDIM;
    float2 pv[5];
    #pragma unroll
    for (int j=0;j<5;++j){
        int idx = t + 64*j;
        float2 rr = rv_[base+idx];
        if (iter > 0){
            float2 pp = pOld[base+idx];
            pv[j] = make_float2(rr.x + beta*pp.x, rr.y + beta*pp.y);
        } else pv[j] = rr;
    }
    if (cg == 0){
        float d = 0.f;
        #pragma unroll
        for (int j=0;j<5;++j){
            pNew[base + t + 64*j] = pv[j];
            d += pv[j].x*pv[j].x + pv[j].y*pv[j].y;
        }
        float wd = wred(d);
        if (t==0) atomicAdd(&scal[16+iter], RHO_*wd);
    }
    int c = cg*4;
    const float2* srow = sP + (long)c*HW + h*NDIM;
    float2 sv[5];
    #pragma unroll
    for (int j=0;j<5;++j) sv[j] = srow[t+64*j];
    #pragma unroll
    for (int c0=0;c0<4;++c0){
        float2 u5[5];
        #pragma unroll
        for (int j=0;j<5;++j) u5[j] = cmulf(sv[j], pv[j]);
        float2 sv2[5];
        if (c0<3){
            const float2* sr2 = srow + (long)(c0+1)*HW;
            #pragma unroll
            for (int j=0;j<5;++j) sv2[j] = sr2[t+64*j];
        }
        wsync();                                   // prior-iter S3 reads done
        s1_from_regs<-1>(A, t, u5);
        wsync();
        s2_stage<-1>(A, t, w40);
        wsync();
        float2 v8[8];
        s3_toregs<-1>(A, t, w320, v8);
        long kb = ((long)(s*NC + c + c0))*HW + h*NDIM;
        if (t < 40){
            #pragma unroll
            for (int cc=0;cc<8;++cc) K[kb + t + 40*cc] = v8[cc];
        }
        if (c0<3){
            #pragma unroll
            for (int j=0;j<5;++j) sv[j]=sv2[j];
        }
    }
}

// ---------------------------------------------------------------------------
// PassB: per (s,c) image, 8-column LDS tile (64B-chunk coalesced loads):
// colFFT -> mask*scale -> colIFFT(adjoint) (doMask=1), or colIFFT only
// (doMask=0, natural in/out via sigma=+1 forward network). In-place on K.
// 512 thr = 8 waves, one column per wave; LDS 20.7KB.
__global__ __launch_bounds__(512) void k_passB(float2* __restrict__ K,
    const float* __restrict__ mscT, int doMask)
{
    constexpr int L = 324;
    int bid = blockIdx.x;
    int wt = bid % 40;
    int sc = bid / 40;
    int s = sc >> 4;
    int tid = threadIdx.x;
    int col = tid >> 6;
    int t = tid & 63;
    int w0 = wt*8;
    __shared__ float2 bufA[8][L];
    float2 w40, w320; make_w(t, w40, w320);
    float mv[8];
    if (doMask && t < 40){
        const float* mcol = mscT + (long)s*HW + (long)(w0+col)*NDIM;
        #pragma unroll
        for (int cc=0;cc<8;++cc) mv[cc] = mcol[t+40*cc];
    }
    long gb = (long)sc*HW;
    int wl = tid & 7, hb = tid >> 3;  // 64B contiguous per 8 lanes
    #pragma unroll
    for (int j=0;j<5;++j){
        int hh = hb + 64*j;
        bufA[wl][hh] = K[gb + (long)hh*NDIM + w0 + wl];
    }
    __syncthreads();
    float2* A = &bufA[col][0];
    if (doMask){
        s1_stage<-1>(A, t);
        wsync();
        s2_stage<-1>(A, t, w40);
        wsync();
        float2 v8[8];
        s3_toregs<-1>(A, t, w320, v8);
        if (t < 40){
            #pragma unroll
            for (int cc=0;cc<8;++cc){ v8[cc].x *= mv[cc]; v8[cc].y *= mv[cc]; }
        }
        wsync();
        a3_fromregs<1>(A, t, w320, v8);
        wsync();
        a2_stage<1>(A, t, w40);
        wsync();
        float2 x5[5];
        a1_toregs<1>(A, t, x5);
        wsync();
        #pragma unroll
        for (int q=0;q<5;++q) A[t + 64*q] = x5[q];
    } else {
        s1_stage<1>(A, t);
        wsync();
        s2_stage<1>(A, t, w40);
        wsync();
        float2 v8[8];
        s3_toregs<1>(A, t, w320, v8);
        wsync();
        if (t < 40){
            #pragma unroll
            for (int cc=0;cc<8;++cc) A[t + 40*cc] = v8[cc];
        }
    }
    __syncthreads();
    #pragma unroll
    for (int j=0;j<5;++j){
        int hh = hb + 64*j;
        K[gb + (long)hh*NDIM + w0 + wl] = bufA[wl][hh];
    }
}

// ---------------------------------------------------------------------------
// PassC2: row inverse (adjoint network) of one coil-group (4 coils),
// conj(s')-combine into part[cg]; optional partial p.part dot. LDS 10.2KB.
__global__ __launch_bounds__(256) void k_passC2(
    const float2* __restrict__ K, const float2* __restrict__ sP,
    const float2* __restrict__ pVec, float2* __restrict__ part,
    float* __restrict__ scal, int dotSlot, int doDot)
{
    int bid = blockIdx.x;
    int cg = bid & 3;
    int hg = (bid>>2) % 80;
    int s  = bid / (4*80);
    int tid = threadIdx.x; int rl = tid>>6; int t = tid&63;
    int h = hg*4 + rl;
    __shared__ float2 bufA[4][NDIM];
    __shared__ float redS[4];
    float2* A = &bufA[rl][0];
    float2 w40, w320; make_w(t, w40, w320);
    int c = cg*4;
    long kb0 = ((long)(s*NC + c))*HW + h*NDIM;
    const float2* srow = sP + (long)c*HW + h*NDIM;
    float2 kv[8], sv[5];
    if (t < 40){
        #pragma unroll
        for (int cc=0;cc<8;++cc) kv[cc] = K[kb0 + t + 40*cc];
    }
    #pragma unroll
    for (int j=0;j<5;++j) sv[j] = srow[t+64*j];
    float2 acc[5];
    #pragma unroll
    for (int j=0;j<5;++j) acc[j]=make_float2(0.f,0.f);
    #pragma unroll
    for (int c0=0;c0<4;++c0){
        a3_fromregs<1>(A, t, w320, kv);
        float2 kv2[8], sv2[5];
        if (c0<3){
            long kb = kb0 + (long)(c0+1)*HW;
            const float2* sr2 = srow + (long)(c0+1)*HW;
            if (t < 40){
                #pragma unroll
                for (int cc=0;cc<8;++cc) kv2[cc] = K[kb + t + 40*cc];
            }
            #pragma unroll
            for (int j=0;j<5;++j) sv2[j] = sr2[t+64*j];
        }
        wsync();
        a2_stage<1>(A, t, w40);
        wsync();
        float2 x5[5];
        a1_toregs<1>(A, t, x5);
        #pragma unroll
        for (int j=0;j<5;++j){
            acc[j].x += sv[j].x*x5[j].x + sv[j].y*x5[j].y;   // conj(s)*u
            acc[j].y += sv[j].x*x5[j].y - sv[j].y*x5[j].x;
        }
        wsync();                                  // a1 reads done before next a3 writes
        if (c0<3){
            #pragma unroll
            for (int cc=0;cc<8;++cc) kv[cc]=kv2[cc];
            #pragma unroll
            for (int j=0;j<5;++j) sv[j]=sv2[j];
        }
    }
    long pbase = (long)s*HW + h*NDIM;
    long obase = ((long)cg*NS + s)*HW + h*NDIM;
    float dot = 0.f;
    #pragma unroll
    for (int j=0;j<5;++j){
        int idx=t+64*j;
        part[obase+idx] = acc[j];
        if (doDot){
            float2 pp = pVec[pbase+idx];
            dot += pp.x*acc[j].x + pp.y*acc[j].y;
        }
    }
    if (doDot){
        float wd = wred(dot);
        if (t==0) redS[rl] = wd;
        __syncthreads();
        if (tid==0) atomicAdd(&scal[dotSlot], redS[0]+redS[1]+redS[2]+redS[3]);
    }
}

// ---------------------------------------------------------------------------
__global__ __launch_bounds__(256) void k_rhs_fin(
    const float2* __restrict__ part, const float2* __restrict__ Iin,
    float2* __restrict__ r, float2* __restrict__ x, float* __restrict__ scal)
{
    __shared__ float red[256];
    int gid = blockIdx.x*blockDim.x + threadIdx.x;
    int gsz = gridDim.x*blockDim.x;
    float rs = 0.f;
    const int NV = NS*HW;
    for (int i = gid; i < NV; i += gsz){
        int w = i % NDIM; int h = (i/NDIM)%NDIM; int s = i/HW;
        float2 iv = Iin[((long)s*NDIM + sh160(h))*NDIM + sh160(w)];
        float2 a0=part[i], a1=part[NV+i], a2=part[2*NV+i], a3=part[3*NV+i];
        float2 rr = make_float2(a0.x+a1.x+a2.x+a3.x + RHO_*iv.x,
                                a0.y+a1.y+a2.y+a3.y + RHO_*iv.y);
        r[i] = rr;
        x[i] = make_float2(0.f,0.f);
        rs += rr.x*rr.x + rr.y*rr.y;
    }
    red[threadIdx.x]=rs; __syncthreads();
    for (int o=128;o>0;o>>=1){ if (threadIdx.x<o) red[threadIdx.x]+=red[threadIdx.x+o]; __syncthreads(); }
    if (threadIdx.x==0) atomicAdd(&scal[0], red[0]);
}

// ---------------------------------------------------------------------------
__global__ __launch_bounds__(256) void k_update(
    float2* __restrict__ x, float2* __restrict__ r,
    const float2* __restrict__ p, const float2* __restrict__ part,
    float* __restrict__ scal, int iter)
{
    __shared__ float red[256];
    float alpha = scal[iter] / (scal[16+iter] + 1e-12f);
    int gid = blockIdx.x*blockDim.x + threadIdx.x;
    int gsz = gridDim.x*blockDim.x;
    float rs = 0.f;
    const int NV = NS*HW;
    for (int i = gid; i < NV; i += gsz){
        float2 a0=part[i], a1=part[NV+i], a2=part[2*NV+i], a3=part[3*NV+i];
        float2 pvv=p[i], xv=x[i], rv=r[i];
        float2 av = make_float2(a0.x+a1.x+a2.x+a3.x + RHO_*pvv.x,
                                a0.y+a1.y+a2.y+a3.y + RHO_*pvv.y);
        xv.x += alpha*pvv.x; xv.y += alpha*pvv.y;
        rv.x -= alpha*av.x;  rv.y -= alpha*av.y;
        x[i]=xv; r[i]=rv;
        rs += rv.x*rv.x + rv.y*rv.y;
    }
    red[threadIdx.x]=rs; __syncthreads();
    for (int o=128;o>0;o>>=1){ if (threadIdx.x<o) red[threadIdx.x]+=red[threadIdx.x+o]; __syncthreads(); }
    if (threadIdx.x==0) atomicAdd(&scal[iter+1], red[0]);
}

__global__ void k_final(const float2* __restrict__ x, float2* __restrict__ out)
{
    int gid = blockIdx.x*blockDim.x + threadIdx.x;
    int gsz = gridDim.x*blockDim.x;
    for (int i = gid; i < NS*HW; i += gsz){
        int w = i % NDIM; int h = (i/NDIM)%NDIM; int s = i/HW;
        out[i] = x[(long)s*HW + sh160(h)*NDIM + sh160(w)];
    }
}

extern "C" void kernel_launch(void* const* d_in, const int* in_sizes, int n_in,
                              void* d_out, int out_size, void* d_ws, size_t ws_size,
                              hipStream_t stream) {
    (void)in_sizes; (void)n_in; (void)out_size; (void)ws_size;
    const float2* kin  = (const float2*)d_in[0];
    const float2* Iin  = (const float2*)d_in[1];
    const float2* csm  = (const float2*)d_in[2];
    const float*  mask = (const float*)d_in[3];

    char* w = (char*)d_ws;
    size_t off = 0;
    float*  scal = (float*)(w+off);  off += 1024;
    float2* sP   = (float2*)(w+off); off += (size_t)NC*HW*8;
    float*  mscT = (float*)(w+off);  off += (size_t)NS*HW*4;
    float2* K    = (float2*)(w+off); off += (size_t)NS*NC*HW*8;
    float2* x    = (float2*)(w+off); off += (size_t)NS*HW*8;
    float2* r    = (float2*)(w+off); off += (size_t)NS*HW*8;
    float2* pA   = (float2*)(w+off); off += (size_t)NS*HW*8;
    float2* pB   = (float2*)(w+off); off += (size_t)NS*HW*8;
    float2* part = (float2*)(w+off); off += (size_t)4*NS*HW*8;

    k_prep<<<2048,256,0,stream>>>(kin, mask, csm, sP, mscT, K, scal);
    k_passB<<<NS*NC*40,512,0,stream>>>(K, mscT, 0);
    k_passC2<<<NS*80*4,256,0,stream>>>(K, sP, r, part, scal, 63, 0);
    k_rhs_fin<<<640,256,0,stream>>>(part, Iin, r, x, scal);

    for (int it=0; it<CG_ITERS; ++it){
        float2* pNew = (it&1)? pB : pA;
        float2* pOld = (it&1)? pA : pB;
        k_passA<<<NS*80*4,256,0,stream>>>(r, pOld, pNew, sP, K, scal, it);
        k_passB<<<NS*NC*40,512,0,stream>>>(K, mscT, 1);
        k_passC2<<<NS*80*4,256,0,stream>>>(K, sP, pNew, part, scal, 16+it, 1);
        k_update<<<640,256,0,stream>>>(x, r, pNew, part, scal, it);
    }
    k_final<<<512,256,0,stream>>>(x, (float2*)d_out);
}

// Round 7
// 1617.039 us; speedup vs baseline: 1.2951x; 1.0389x over previous
//
#include <hip/hip_runtime.h>
#include <math.h>

// ---------------------------------------------------------------------------
// SENSE CG reconstruction, B=1, S=4, C=16, H=W=320, rho=0.1, 15 CG iters.
// Conjugated by fftshift (even N): CG loop uses plain FFTs; final
// ifft2c(fft2c(x)) == x skipped.
// R6: FFT-320 = Stockham {5,8,8}; stage1 radix-5 in registers; stage3
//     direct to/from global (natural order); inverse = adjoint network.
// R7: ALL complex math on ext_vector_type(2) floats so clang emits packed
//     fp32 (v_pk_add/mul/fma_f32, full-rate on CDNA4 = the 157 TF path).
//     R6 evidence: kernels flipped to VALU-issue-bound (~450 VALU vs ~29
//     DS instr per coil-line); scalar fp32 runs at half the packed rate.
// ---------------------------------------------------------------------------

#define NDIM 320
#define HHALF 160
#define HW (NDIM*NDIM)
#define NS 4
#define NC 16
#define RHO_ 0.1f
#define CG_ITERS 15

typedef float v2f __attribute__((ext_vector_type(2)));

__device__ __forceinline__ void wsync(){
    __builtin_amdgcn_fence(__ATOMIC_ACQ_REL, "wavefront");
    __builtin_amdgcn_wave_barrier();
}

__device__ __forceinline__ float wred(float v){
    #pragma unroll
    for (int o=32;o>0;o>>=1) v += __shfl_down(v,o,64);
    return v;  // valid on lane 0
}

// complex mul: (a.x b.x - a.y b.y, a.x b.y + a.y b.x) -> 2 packed FMAs
__device__ __forceinline__ v2f cmulf(v2f a, v2f b){
    return (v2f){a.x,a.x}*b + (v2f){-a.y,a.y}*(v2f){b.y,b.x};
}

// multiply by stored forward twiddle (SIGMA=-1) or its conjugate (SIGMA=+1)
template<int SIGMA>
__device__ __forceinline__ v2f cmulw(v2f a, v2f w){
    v2f wb = (SIGMA<0) ? w : (v2f){w.x, -w.y};
    return cmulf(a, wb);
}

template<int SIGMA>
__device__ __forceinline__ v2f mulj(v2f z){  // SIGMA*i*z
    return (v2f){ -(float)SIGMA*z.y, (float)SIGMA*z.x };
}

template<int SIGMA>
__device__ __forceinline__ void radix5(const v2f* u, v2f* v){
    const float C1 = 0.30901699437494742f, S1 = 0.95105651629515357f;
    const float C2 = -0.80901699437494745f, S2 = 0.58778525229247312f;
    v2f t1=u[1]+u[4], t2=u[2]+u[3], t3=u[1]-u[4], t4=u[2]-u[3];
    v[0] = u[0] + t1 + t2;
    v2f m1 = u[0] + t1*C1 + t2*C2;
    v2f m2 = u[0] + t1*C2 + t2*C1;
    v2f n1 = t3*S1 + t4*S2;
    v2f n2 = t3*S2 - t4*S1;
    v2f j1 = mulj<SIGMA>(n1), j2 = mulj<SIGMA>(n2);
    v[1]=m1+j1; v[4]=m1-j1; v[2]=m2+j2; v[3]=m2-j2;
}

template<int SIGMA>
__device__ __forceinline__ void dft8(const v2f* u, v2f* y){
    const float C = 0.70710678118654752f;
    v2f a0=u[0]+u[4], a1=u[0]-u[4];
    v2f a2=u[2]+u[6], a3=u[2]-u[6];
    v2f a4=u[1]+u[5], a5=u[1]-u[5];
    v2f a6=u[3]+u[7], a7=u[3]-u[7];
    v2f j3 = mulj<SIGMA>(a3);
    v2f E0=a0+a2, E2=a0-a2;
    v2f E1=a1+j3, E3=a1-j3;
    v2f j7 = mulj<SIGMA>(a7);
    v2f O0=a4+a6, O2=a4-a6;
    v2f O1=a5+j7, O3=a5-j7;
    v2f W1 = (O1 + mulj<SIGMA>(O1)) * C;     // w^1 * O1
    v2f jO2 = mulj<SIGMA>(O2);               // w^2 * O2
    v2f W3 = (mulj<SIGMA>(O3) - O3) * C;     // w^3 * O3
    y[0]=E0+O0; y[4]=E0-O0;
    y[1]=E1+W1; y[5]=E1-W1;
    y[2]=E2+jO2; y[6]=E2-jO2;
    y[3]=E3+W3; y[7]=E3-W3;
}

// ---- forward Stockham {5,8,8}: natural in -> natural out -------------------
// S1: butterfly t: in x[t+64q] -> out A[5t+c].
template<int SIGMA>
__device__ __forceinline__ void s1_from_regs(v2f* __restrict__ A, int t,
                                             const v2f* u5){
    v2f v[5];
    radix5<SIGMA>(u5, v);
    #pragma unroll
    for (int c=0;c<5;++c) A[5*t + c] = v[c];
}

template<int SIGMA>
__device__ __forceinline__ void s1_stage(v2f* __restrict__ A, int t){
    v2f u[5];
    #pragma unroll
    for (int q=0;q<5;++q) u[q] = A[t + 64*q];
    wsync();
    s1_from_regs<SIGMA>(A, t, u);
}

// S2: P=5. butterfly i=t<40: read A[t+40q], twiddle W_40^{q*(t%5)}, dft8,
//     write A[(t/5)*40 + t%5 + 5c].
template<int SIGMA>
__device__ __forceinline__ void s2_stage(v2f* __restrict__ A, int t, v2f w40){
    if (t < 40){
        v2f u[8];
        #pragma unroll
        for (int q=0;q<8;++q) u[q] = A[t + 40*q];
        wsync();
        v2f wc = w40;
        u[1] = cmulw<SIGMA>(u[1], wc);
        #pragma unroll
        for (int q=2;q<8;++q){ wc = cmulf(wc, w40); u[q] = cmulw<SIGMA>(u[q], wc); }
        v2f v[8];
        dft8<SIGMA>(u, v);
        int k = t % 5, jb = t / 5;
        int base = jb*40 + k;
        #pragma unroll
        for (int c=0;c<8;++c) A[base + 5*c] = v[c];
    }
}

// S3: P=40. butterfly i=t<40: read A[t+40q], twiddle W_320^{q*t}, dft8 ->
//     v[c] = X[t+40c] (registers; caller stores).
template<int SIGMA>
__device__ __forceinline__ void s3_toregs(const v2f* __restrict__ A, int t,
                                          v2f w320, v2f* v){
    if (t < 40){
        v2f u[8];
        #pragma unroll
        for (int q=0;q<8;++q) u[q] = A[t + 40*q];
        v2f wc = w320;
        u[1] = cmulw<SIGMA>(u[1], wc);
        #pragma unroll
        for (int q=2;q<8;++q){ wc = cmulf(wc, w320); u[q] = cmulw<SIGMA>(u[q], wc); }
        dft8<SIGMA>(u, v);
    }
}

// ---- adjoint network (unnormalized inverse), X[t+40c] regs -> natural -----
template<int SIGMA>
__device__ __forceinline__ void a3_fromregs(v2f* __restrict__ A, int t,
                                            v2f w320, const v2f* vin){
    if (t < 40){
        v2f u[8];
        dft8<SIGMA>(vin, u);
        v2f wc = w320;
        u[1] = cmulw<SIGMA>(u[1], wc);
        #pragma unroll
        for (int q=2;q<8;++q){ wc = cmulf(wc, w320); u[q] = cmulw<SIGMA>(u[q], wc); }
        #pragma unroll
        for (int q=0;q<8;++q) A[t + 40*q] = u[q];
    }
}

template<int SIGMA>
__device__ __forceinline__ void a2_stage(v2f* __restrict__ A, int t, v2f w40){
    if (t < 40){
        int k = t % 5, jb = t / 5;
        int base = jb*40 + k;
        v2f v[8];
        #pragma unroll
        for (int c=0;c<8;++c) v[c] = A[base + 5*c];
        wsync();
        v2f u[8];
        dft8<SIGMA>(v, u);
        v2f wc = w40;
        u[1] = cmulw<SIGMA>(u[1], wc);
        #pragma unroll
        for (int q=2;q<8;++q){ wc = cmulf(wc, w40); u[q] = cmulw<SIGMA>(u[q], wc); }
        #pragma unroll
        for (int q=0;q<8;++q) A[t + 40*q] = u[q];
    }
}

template<int SIGMA>
__device__ __forceinline__ void a1_toregs(const v2f* __restrict__ A, int t,
                                          v2f* out5){
    v2f v[5];
    #pragma unroll
    for (int c=0;c<5;++c) v[c] = A[5*t + c];
    radix5<SIGMA>(v, out5);
}

__device__ __forceinline__ void make_w(int t, v2f& w40, v2f& w320){
    float sn, cs;
    const float n2pi = -6.283185307179586f;
    __sincosf(n2pi*(float)(t%5)/40.f, &sn, &cs); w40  = (v2f){cs, sn};
    __sincosf(n2pi*(float)t/320.f,    &sn, &cs); w320 = (v2f){cs, sn};
}

__device__ __forceinline__ int sh160(int i){ return i < HHALF ? i + HHALF : i - HHALF; }

// ---------------------------------------------------------------------------
__global__ void k_prep(const v2f* __restrict__ kin, const float* __restrict__ mask,
                       const v2f* __restrict__ csm, v2f* __restrict__ sP,
                       float* __restrict__ mscT, v2f* __restrict__ K,
                       float* __restrict__ scal)
{
    int gid = blockIdx.x*blockDim.x + threadIdx.x;
    int gsz = gridDim.x*blockDim.x;
    if (gid < 64) scal[gid] = 0.f;
    for (int i = gid; i < NC*HW; i += gsz){
        int w = i % NDIM; int h = (i/NDIM) % NDIM; int c = i/HW;
        sP[i] = csm[(c*NDIM + sh160(h))*NDIM + sh160(w)];
    }
    for (int i = gid; i < NS*HW; i += gsz){
        int h = i % NDIM; int wc = (i/NDIM)%NDIM; int s = i/HW;
        float m = mask[(s*NDIM + sh160(h))*NDIM + sh160(wc)];
        mscT[i] = m*m*(1.0f/102400.0f);
    }
    for (int i = gid; i < NS*NC*HW; i += gsz){
        int w = i % NDIM; int h = (i/NDIM)%NDIM; int sc = i/HW;
        int s = sc >> 4;
        int hs = sh160(h), ws = sh160(w);
        float m = mask[(s*NDIM + hs)*NDIM + ws];
        v2f kv = kin[((long)sc*NDIM + hs)*NDIM + ws];
        float f = m*(1.0f/320.0f);
        K[i] = kv * f;
    }
}

// ---------------------------------------------------------------------------
// PassA: p = r + beta*p fused; K[s,c,h,:] = rowFFT(s'_c .* p).
// grid = S*80*4 ; 256 thr = 4 waves, one row per wave. LDS 10.2KB.
__global__ __launch_bounds__(256) void k_passA(
    const v2f* __restrict__ rv_, const v2f* __restrict__ pOld,
    v2f* __restrict__ pNew, const v2f* __restrict__ sP,
    v2f* __restrict__ K, float* __restrict__ scal, int iter)
{
    int bid = blockIdx.x;
    int cg = bid & 3;
    int hg = (bid>>2) % 80;
    int s  = bid / (4*80);
    int tid = threadIdx.x; int rl = tid>>6; int t = tid&63;
    int h = hg*4 + rl;
    __shared__ v2f bufA[4][NDIM];
    v2f* A = &bufA[rl][0];
    v2f w40, w320; make_w(t, w40, w320);
    float beta = 0.f;
    if (iter > 0) beta = scal[iter] / (scal[iter-1] + 1e-12f);
    long base = (long)s*HW + h*NDIM;
    v2f pv[5];
    #pragma unroll
    for (int j=0;j<5;++j){
        int idx = t + 64*j;
        v2f rr = rv_[base+idx];
        if (iter > 0){
            v2f pp = pOld[base+idx];
            pv[j] = rr + pp*beta;
        } else pv[j] = rr;
    }
    if (cg == 0){
        float d = 0.f;
        #pragma unroll
        for (int j=0;j<5;++j){
            pNew[base + t + 64*j] = pv[j];
            d += pv[j].x*pv[j].x + pv[j].y*pv[j].y;
        }
        float wd = wred(d);
        if (t==0) atomicAdd(&scal[16+iter], RHO_*wd);
    }
    int c = cg*4;
    const v2f* srow = sP + (long)c*HW + h*NDIM;
    v2f sv[5];
    #pragma unroll
    for (int j=0;j<5;++j) sv[j] = srow[t+64*j];
    #pragma unroll
    for (int c0=0;c0<4;++c0){
        v2f u5[5];
        #pragma unroll
        for (int j=0;j<5;++j) u5[j] = cmulf(sv[j], pv[j]);
        v2f sv2[5];
        if (c0<3){
            const v2f* sr2 = srow + (long)(c0+1)*HW;
            #pragma unroll
            for (int j=0;j<5;++j) sv2[j] = sr2[t+64*j];
        }
        wsync();                                   // prior-iter S3 reads done
        s1_from_regs<-1>(A, t, u5);
        wsync();
        s2_stage<-1>(A, t, w40);
        wsync();
        v2f v8[8];
        s3_toregs<-1>(A, t, w320, v8);
        long kb = ((long)(s*NC + c + c0))*HW + h*NDIM;
        if (t < 40){
            #pragma unroll
            for (int cc=0;cc<8;++cc) K[kb + t + 40*cc] = v8[cc];
        }
        if (c0<3){
            #pragma unroll
            for (int j=0;j<5;++j) sv[j]=sv2[j];
        }
    }
}

// ---------------------------------------------------------------------------
// PassB: per (s,c) image, 8-column LDS tile (64B-chunk coalesced loads):
// colFFT -> mask*scale -> colIFFT(adjoint) (doMask=1), or colIFFT only
// (doMask=0, sigma=+1 forward network). In-place on K.
// 512 thr = 8 waves, one column per wave; LDS 20.7KB.
__global__ __launch_bounds__(512) void k_passB(v2f* __restrict__ K,
    const float* __restrict__ mscT, int doMask)
{
    constexpr int L = 324;
    int bid = blockIdx.x;
    int wt = bid % 40;
    int sc = bid / 40;
    int s = sc >> 4;
    int tid = threadIdx.x;
    int col = tid >> 6;
    int t = tid & 63;
    int w0 = wt*8;
    __shared__ v2f bufA[8][L];
    v2f w40, w320; make_w(t, w40, w320);
    float mv[8];
    if (doMask && t < 40){
        const float* mcol = mscT + (long)s*HW + (long)(w0+col)*NDIM;
        #pragma unroll
        for (int cc=0;cc<8;++cc) mv[cc] = mcol[t+40*cc];
    }
    long gb = (long)sc*HW;
    int wl = tid & 7, hb = tid >> 3;  // 64B contiguous per 8 lanes
    #pragma unroll
    for (int j=0;j<5;++j){
        int hh = hb + 64*j;
        bufA[wl][hh] = K[gb + (long)hh*NDIM + w0 + wl];
    }
    __syncthreads();
    v2f* A = &bufA[col][0];
    if (doMask){
        s1_stage<-1>(A, t);
        wsync();
        s2_stage<-1>(A, t, w40);
        wsync();
        v2f v8[8];
        s3_toregs<-1>(A, t, w320, v8);
        if (t < 40){
            #pragma unroll
            for (int cc=0;cc<8;++cc) v8[cc] = v8[cc]*mv[cc];
        }
        wsync();
        a3_fromregs<1>(A, t, w320, v8);
        wsync();
        a2_stage<1>(A, t, w40);
        wsync();
        v2f x5[5];
        a1_toregs<1>(A, t, x5);
        wsync();
        #pragma unroll
        for (int q=0;q<5;++q) A[t + 64*q] = x5[q];
    } else {
        s1_stage<1>(A, t);
        wsync();
        s2_stage<1>(A, t, w40);
        wsync();
        v2f v8[8];
        s3_toregs<1>(A, t, w320, v8);
        wsync();
        if (t < 40){
            #pragma unroll
            for (int cc=0;cc<8;++cc) A[t + 40*cc] = v8[cc];
        }
    }
    __syncthreads();
    #pragma unroll
    for (int j=0;j<5;++j){
        int hh = hb + 64*j;
        K[gb + (long)hh*NDIM + w0 + wl] = bufA[wl][hh];
    }
}

// ---------------------------------------------------------------------------
// PassC2: row inverse (adjoint network) of one coil-group (4 coils),
// conj(s')-combine into part[cg]; optional partial p.part dot. LDS 10.2KB.
__global__ __launch_bounds__(256) void k_passC2(
    const v2f* __restrict__ K, const v2f* __restrict__ sP,
    const v2f* __restrict__ pVec, v2f* __restrict__ part,
    float* __restrict__ scal, int dotSlot, int doDot)
{
    int bid = blockIdx.x;
    int cg = bid & 3;
    int hg = (bid>>2) % 80;
    int s  = bid / (4*80);
    int tid = threadIdx.x; int rl = tid>>6; int t = tid&63;
    int h = hg*4 + rl;
    __shared__ v2f bufA[4][NDIM];
    __shared__ float redS[4];
    v2f* A = &bufA[rl][0];
    v2f w40, w320; make_w(t, w40, w320);
    int c = cg*4;
    long kb0 = ((long)(s*NC + c))*HW + h*NDIM;
    const v2f* srow = sP + (long)c*HW + h*NDIM;
    v2f kv[8], sv[5];
    if (t < 40){
        #pragma unroll
        for (int cc=0;cc<8;++cc) kv[cc] = K[kb0 + t + 40*cc];
    }
    #pragma unroll
    for (int j=0;j<5;++j) sv[j] = srow[t+64*j];
    v2f acc[5];
    #pragma unroll
    for (int j=0;j<5;++j) acc[j]=(v2f){0.f,0.f};
    #pragma unroll
    for (int c0=0;c0<4;++c0){
        a3_fromregs<1>(A, t, w320, kv);
        v2f kv2[8], sv2[5];
        if (c0<3){
            long kb = kb0 + (long)(c0+1)*HW;
            const v2f* sr2 = srow + (long)(c0+1)*HW;
            if (t < 40){
                #pragma unroll
                for (int cc=0;cc<8;++cc) kv2[cc] = K[kb + t + 40*cc];
            }
            #pragma unroll
            for (int j=0;j<5;++j) sv2[j] = sr2[t+64*j];
        }
        wsync();
        a2_stage<1>(A, t, w40);
        wsync();
        v2f x5[5];
        a1_toregs<1>(A, t, x5);
        #pragma unroll
        for (int j=0;j<5;++j){
            // acc += conj(s)*u  (2 packed FMAs)
            acc[j] += (v2f){sv[j].x,sv[j].x}*x5[j]
                    + (v2f){sv[j].y,-sv[j].y}*(v2f){x5[j].y,x5[j].x};
        }
        wsync();                   // a1 reads done before next a3 writes
        if (c0<3){
            #pragma unroll
            for (int cc=0;cc<8;++cc) kv[cc]=kv2[cc];
            #pragma unroll
            for (int j=0;j<5;++j) sv[j]=sv2[j];
        }
    }
    long pbase = (long)s*HW + h*NDIM;
    long obase = ((long)cg*NS + s)*HW + h*NDIM;
    float dot = 0.f;
    #pragma unroll
    for (int j=0;j<5;++j){
        int idx=t+64*j;
        part[obase+idx] = acc[j];
        if (doDot){
            v2f pp = pVec[pbase+idx];
            dot += pp.x*acc[j].x + pp.y*acc[j].y;
        }
    }
    if (doDot){
        float wd = wred(dot);
        if (t==0) redS[rl] = wd;
        __syncthreads();
        if (tid==0) atomicAdd(&scal[dotSlot], redS[0]+redS[1]+redS[2]+redS[3]);
    }
}

// ---------------------------------------------------------------------------
__global__ __launch_bounds__(256) void k_rhs_fin(
    const v2f* __restrict__ part, const v2f* __restrict__ Iin,
    v2f* __restrict__ r, v2f* __restrict__ x, float* __restrict__ scal)
{
    __shared__ float red[256];
    int gid = blockIdx.x*blockDim.x + threadIdx.x;
    int gsz = gridDim.x*blockDim.x;
    float rs = 0.f;
    const int NV = NS*HW;
    for (int i = gid; i < NV; i += gsz){
        int w = i % NDIM; int h = (i/NDIM)%NDIM; int s = i/HW;
        v2f iv = Iin[((long)s*NDIM + sh160(h))*NDIM + sh160(w)];
        v2f rr = part[i] + part[NV+i] + part[2*NV+i] + part[3*NV+i] + iv*RHO_;
        r[i] = rr;
        x[i] = (v2f){0.f,0.f};
        rs += rr.x*rr.x + rr.y*rr.y;
    }
    red[threadIdx.x]=rs; __syncthreads();
    for (int o=128;o>0;o>>=1){ if (threadIdx.x<o) red[threadIdx.x]+=red[threadIdx.x+o]; __syncthreads(); }
    if (threadIdx.x==0) atomicAdd(&scal[0], red[0]);
}

// ---------------------------------------------------------------------------
__global__ __launch_bounds__(256) void k_update(
    v2f* __restrict__ x, v2f* __restrict__ r,
    const v2f* __restrict__ p, const v2f* __restrict__ part,
    float* __restrict__ scal, int iter)
{
    __shared__ float red[256];
    float alpha = scal[iter] / (scal[16+iter] + 1e-12f);
    int gid = blockIdx.x*blockDim.x + threadIdx.x;
    int gsz = gridDim.x*blockDim.x;
    float rs = 0.f;
    const int NV = NS*HW;
    for (int i = gid; i < NV; i += gsz){
        v2f pvv=p[i];
        v2f av = part[i] + part[NV+i] + part[2*NV+i] + part[3*NV+i] + pvv*RHO_;
        v2f xv = x[i] + pvv*alpha;
        v2f rv = r[i] - av*alpha;
        x[i]=xv; r[i]=rv;
        rs += rv.x*rv.x + rv.y*rv.y;
    }
    red[threadIdx.x]=rs; __syncthreads();
    for (int o=128;o>0;o>>=1){ if (threadIdx.x<o) red[threadIdx.x]+=red[threadIdx.x+o]; __syncthreads(); }
    if (threadIdx.x==0) atomicAdd(&scal[iter+1], red[0]);
}

__global__ void k_final(const v2f* __restrict__ x, v2f* __restrict__ out)
{
    int gid = blockIdx.x*blockDim.x + threadIdx.x;
    int gsz = gridDim.x*blockDim.x;
    for (int i = gid; i < NS*HW; i += gsz){
        int w = i % NDIM; int h = (i/NDIM)%NDIM; int s = i/HW;
        out[i] = x[(long)s*HW + sh160(h)*NDIM + sh160(w)];
    }
}

extern "C" void kernel_launch(void* const* d_in, const int* in_sizes, int n_in,
                              void* d_out, int out_size, void* d_ws, size_t ws_size,
                              hipStream_t stream) {
    (void)in_sizes; (void)n_in; (void)out_size; (void)ws_size;
    const v2f* kin  = (const v2f*)d_in[0];
    const v2f* Iin  = (const v2f*)d_in[1];
    const v2f* csm  = (const v2f*)d_in[2];
    const float* mask = (const float*)d_in[3];

    char* w = (char*)d_ws;
    size_t off = 0;
    float* scal = (float*)(w+off);  off += 1024;
    v2f* sP   = (v2f*)(w+off); off += (size_t)NC*HW*8;
    float* mscT = (float*)(w+off); off += (size_t)NS*HW*4;
    v2f* K    = (v2f*)(w+off); off += (size_t)NS*NC*HW*8;
    v2f* x    = (v2f*)(w+off); off += (size_t)NS*HW*8;
    v2f* r    = (v2f*)(w+off); off += (size_t)NS*HW*8;
    v2f* pA   = (v2f*)(w+off); off += (size_t)NS*HW*8;
    v2f* pB   = (v2f*)(w+off); off += (size_t)NS*HW*8;
    v2f* part = (v2f*)(w+off); off += (size_t)4*NS*HW*8;

    k_prep<<<2048,256,0,stream>>>(kin, mask, csm, sP, mscT, K, scal);
    k_passB<<<NS*NC*40,512,0,stream>>>(K, mscT, 0);
    k_passC2<<<NS*80*4,256,0,stream>>>(K, sP, r, part, scal, 63, 0);
    k_rhs_fin<<<640,256,0,stream>>>(part, Iin, r, x, scal);

    for (int it=0; it<CG_ITERS; ++it){
        v2f* pNew = (it&1)? pB : pA;
        v2f* pOld = (it&1)? pA : pB;
        k_passA<<<NS*80*4,256,0,stream>>>(r, pOld, pNew, sP, K, scal, it);
        k_passB<<<NS*NC*40,512,0,stream>>>(K, mscT, 1);
        k_passC2<<<NS*80*4,256,0,stream>>>(K, sP, pNew, part, scal, 16+it, 1);
        k_update<<<640,256,0,stream>>>(x, r, pNew, part, scal, it);
    }
    k_final<<<512,256,0,stream>>>(x, (v2f*)d_out);
}